// Round 1
// baseline (359.507 us; speedup 1.0000x reference)
//
#include <hip/hip_runtime.h>
#include <math.h>

#define IN_F 128
#define OUT_F 64
#define ALPHA 0.2f
#define INV_SQRT_F 0.125f   // 1/sqrt(OUT_F)

// ---------------------------------------------------------------------------
// Kernel 1: data = h @ W^T + b ; s_src = data @ a[:64] ; s_dst = data @ a[64:]
// wave = node (64 lanes = 64 output features), 4 nodes per 256-thread block.
// W staged in LDS with +1 padding (stride 129 -> bank (f+k)%32, 2-way = free).
// ---------------------------------------------------------------------------
__global__ __launch_bounds__(256) void k_linear(
    const float* __restrict__ h, const float* __restrict__ W,
    const float* __restrict__ b, const float* __restrict__ a,
    float* __restrict__ data, float* __restrict__ s_src,
    float* __restrict__ s_dst, int n_nodes)
{
    __shared__ float Wl[OUT_F * (IN_F + 1)];
    __shared__ float hl[4 * IN_F];
    const int tid = threadIdx.x;

    // stage W (64x128 = 8192 floats), coalesced global reads
    for (int i = tid; i < OUT_F * IN_F; i += 256) {
        int f = i >> 7, k = i & 127;
        Wl[f * (IN_F + 1) + k] = W[i];
    }
    // stage 4 contiguous h rows (512 floats), coalesced
    const int node0 = blockIdx.x * 4;
    for (int i = tid; i < 4 * IN_F; i += 256) {
        int n = node0 + (i >> 7);
        hl[i] = (n < n_nodes) ? h[(size_t)node0 * IN_F + i] : 0.f;
    }
    __syncthreads();

    const int nl = tid >> 6;      // local node 0..3
    const int f  = tid & 63;      // output feature
    const int n  = node0 + nl;

    float acc = b[f];
    const float* hr = &hl[nl * IN_F];
    const float* wr = &Wl[f * (IN_F + 1)];
    #pragma unroll
    for (int k = 0; k < IN_F; ++k)
        acc = fmaf(hr[k], wr[k], acc);

    // per-node attention projections, wave-64 butterfly reduce
    float ps = acc * a[f];
    float pd = acc * a[OUT_F + f];
    #pragma unroll
    for (int m = 32; m >= 1; m >>= 1) {
        ps += __shfl_xor(ps, m, 64);
        pd += __shfl_xor(pd, m, 64);
    }

    if (n < n_nodes) {
        data[(size_t)n * OUT_F + f] = acc;
        if (f == 0) { s_src[n] = ps; s_dst[n] = pd; }
    }
}

// ---------------------------------------------------------------------------
// Kernel 2: per edge e: w = exp(leaky_relu(s_src[src]+s_dst[dst]) * 0.125)
//   out[src,:] += w * data[dst,:]  (64 scalar atomics, coalesced addresses)
//   rowsum[src] += w               (lane 0)
// one wave per edge, 4 edges per block.
// ---------------------------------------------------------------------------
__global__ __launch_bounds__(256) void k_edge(
    const int* __restrict__ src_arr, const int* __restrict__ dst_arr,
    const float* __restrict__ s_src, const float* __restrict__ s_dst,
    const float* __restrict__ data, float* __restrict__ out,
    float* __restrict__ rowsum, int n_edges)
{
    const int e = (int)((blockIdx.x * 256u + threadIdx.x) >> 6);
    const int lane = threadIdx.x & 63;
    if (e >= n_edges) return;

    const int s = src_arr[e];
    const int d = dst_arr[e];
    float sc = s_src[s] + s_dst[d];
    float lr = sc > 0.f ? sc : ALPHA * sc;
    float w  = expf(lr * INV_SQRT_F);

    atomicAdd(&out[(size_t)s * OUT_F + lane],
              w * data[(size_t)d * OUT_F + lane]);
    if (lane == 0) atomicAdd(&rowsum[s], w);
}

// ---------------------------------------------------------------------------
// Kernel 3: h_prime = (acc + row_zero*data) / (row_zero ? 1 : rowsum)
// ---------------------------------------------------------------------------
__global__ __launch_bounds__(256) void k_final(
    const float* __restrict__ data, const float* __restrict__ rowsum,
    float* __restrict__ out, int total)
{
    const int i = blockIdx.x * 256 + threadIdx.x;
    if (i >= total) return;
    const int n = i >> 6;          // OUT_F == 64
    const float rs = rowsum[n];
    float o = out[i];
    o = (rs == 0.f) ? data[i] : (o / rs);
    out[i] = o;
}

extern "C" void kernel_launch(void* const* d_in, const int* in_sizes, int n_in,
                              void* d_out, int out_size, void* d_ws, size_t ws_size,
                              hipStream_t stream)
{
    const float* h   = (const float*)d_in[0];
    const int*   adj = (const int*)  d_in[1];   // (2, E) int32
    const float* W   = (const float*)d_in[2];   // (64, 128)
    const float* b   = (const float*)d_in[3];   // (64,)
    const float* a   = (const float*)d_in[4];   // (1, 128)
    float* out = (float*)d_out;

    const int n_nodes = in_sizes[0] / IN_F;
    const int n_edges = in_sizes[1] / 2;

    // workspace layout (f32): data[N*64] | s_src[N] | s_dst[N] | rowsum[N]
    float* data   = (float*)d_ws;
    float* s_src  = data  + (size_t)n_nodes * OUT_F;
    float* s_dst  = s_src + n_nodes;
    float* rowsum = s_dst + n_nodes;

    hipMemsetAsync(d_out, 0, (size_t)out_size * sizeof(float), stream);
    hipMemsetAsync(rowsum, 0, (size_t)n_nodes * sizeof(float), stream);

    k_linear<<<(n_nodes + 3) / 4, 256, 0, stream>>>(
        h, W, b, a, data, s_src, s_dst, n_nodes);

    k_edge<<<(n_edges + 3) / 4, 256, 0, stream>>>(
        adj, adj + n_edges, s_src, s_dst, data, out, rowsum, n_edges);

    const int total = n_nodes * OUT_F;
    k_final<<<(total + 255) / 256, 256, 0, stream>>>(data, rowsum, out, total);
}

// Round 2
// 315.137 us; speedup vs baseline: 1.1408x; 1.1408x over previous
//
#include <hip/hip_runtime.h>
#include <math.h>

#define IN_F 128
#define OUT_F 64
#define ALPHA 0.2f
#define INV_SQRT_F 0.125f   // 1/sqrt(OUT_F)
#define W_STRIDE 132        // 128+4: keeps 16B alignment; b128 reads spread 8 words/bank (even)

// ---------------------------------------------------------------------------
// k_linear: data = h@W^T + b ; s_src = data@a[:64] ; s_dst = data@a[64:]
// wave = 4 nodes (16 nodes/block). W in LDS (stride 132, float4 reads).
// h read via wave-uniform global float4 loads (L1 broadcast, off the LDS pipe).
// Also fused: histogram deg[src]++ for the CSR build (independent work).
// ---------------------------------------------------------------------------
__global__ __launch_bounds__(256) void k_linear(
    const float* __restrict__ h, const float* __restrict__ W,
    const float* __restrict__ b, const float* __restrict__ a,
    const int* __restrict__ src, float* __restrict__ data,
    float* __restrict__ s_src, float* __restrict__ s_dst,
    int* __restrict__ deg, int n_nodes, int n_edges)
{
    __shared__ float Wl[OUT_F * W_STRIDE];   // 33792 B
    const int tid = threadIdx.x;

    // fused histogram: this block's slice of edges (deg pre-zeroed by memset)
    {
        int e = blockIdx.x * 256 + tid;
        if (e < n_edges) atomicAdd(&deg[src[e]], 1);
    }

    // stage W: 64x128 floats, coalesced global reads
    for (int i = tid; i < OUT_F * IN_F; i += 256) {
        int f = i >> 7, k = i & 127;
        Wl[f * W_STRIDE + k] = W[i];
    }
    __syncthreads();

    const int wv_ = tid >> 6;     // wave in block
    const int f   = tid & 63;     // output feature
    const int node0 = blockIdx.x * 16 + wv_ * 4;

    const int nclamp = n_nodes - 1;
    const int n0 = min(node0 + 0, nclamp);
    const int n1 = min(node0 + 1, nclamp);
    const int n2 = min(node0 + 2, nclamp);
    const int n3 = min(node0 + 3, nclamp);
    const float4* __restrict__ hp0 = (const float4*)(h + (size_t)n0 * IN_F);
    const float4* __restrict__ hp1 = (const float4*)(h + (size_t)n1 * IN_F);
    const float4* __restrict__ hp2 = (const float4*)(h + (size_t)n2 * IN_F);
    const float4* __restrict__ hp3 = (const float4*)(h + (size_t)n3 * IN_F);
    const float4* __restrict__ wp  = (const float4*)&Wl[f * W_STRIDE]; // 528B*f, 16B aligned

    float acc0 = 0.f, acc1 = 0.f, acc2 = 0.f, acc3 = 0.f;
    #pragma unroll 8
    for (int c = 0; c < IN_F / 4; ++c) {
        float4 wv = wp[c];
        float4 x0 = hp0[c], x1 = hp1[c], x2 = hp2[c], x3 = hp3[c];
        acc0 = fmaf(wv.x, x0.x, fmaf(wv.y, x0.y, fmaf(wv.z, x0.z, fmaf(wv.w, x0.w, acc0))));
        acc1 = fmaf(wv.x, x1.x, fmaf(wv.y, x1.y, fmaf(wv.z, x1.z, fmaf(wv.w, x1.w, acc1))));
        acc2 = fmaf(wv.x, x2.x, fmaf(wv.y, x2.y, fmaf(wv.z, x2.z, fmaf(wv.w, x2.w, acc2))));
        acc3 = fmaf(wv.x, x3.x, fmaf(wv.y, x3.y, fmaf(wv.z, x3.z, fmaf(wv.w, x3.w, acc3))));
    }

    const float bv = b[f];
    const float as = a[f];
    const float ad = a[OUT_F + f];
    acc0 += bv; acc1 += bv; acc2 += bv; acc3 += bv;

    float accs[4] = {acc0, acc1, acc2, acc3};
    #pragma unroll
    for (int i2 = 0; i2 < 4; ++i2) {
        float acc = accs[i2];
        int n = node0 + i2;
        float ps = acc * as, pd = acc * ad;
        #pragma unroll
        for (int m = 32; m >= 1; m >>= 1) {
            ps += __shfl_xor(ps, m, 64);
            pd += __shfl_xor(pd, m, 64);
        }
        if (n < n_nodes) {
            data[(size_t)n * OUT_F + f] = acc;
            if (f == 0) { s_src[n] = ps; s_dst[n] = pd; }
        }
    }
}

// ---------------------------------------------------------------------------
// k_scan: exclusive prefix sum of deg -> start & cursor. Single block, 1024
// threads, wave-shuffle scan (2 barriers per 1024-chunk, not 20).
// ---------------------------------------------------------------------------
__global__ __launch_bounds__(1024) void k_scan(
    const int* __restrict__ deg, int* __restrict__ start,
    int* __restrict__ cursor, int n)
{
    __shared__ int wsum[16];
    __shared__ int woff[16];
    const int tid = threadIdx.x, lane = tid & 63, w = tid >> 6;
    int running = 0;
    for (int base = 0; base < n; base += 1024) {
        int i = base + tid;
        int v = (i < n) ? deg[i] : 0;
        int x = v;
        #pragma unroll
        for (int off = 1; off < 64; off <<= 1) {
            int t = __shfl_up(x, off, 64);
            if (lane >= off) x += t;
        }
        if (lane == 63) wsum[w] = x;
        __syncthreads();
        if (w == 0 && lane < 16) {
            int s = wsum[lane];
            #pragma unroll
            for (int off = 1; off < 16; off <<= 1) {
                int t = __shfl_up(s, off, 16);
                if ((lane & 15) >= off) s += t;
            }
            woff[lane] = s - wsum[lane];   // exclusive wave offset
        }
        __syncthreads();
        int excl = running + woff[w] + x - v;
        if (i < n) { start[i] = excl; cursor[i] = excl; }
        running += woff[15] + wsum[15];
        __syncthreads();   // protect wsum/woff before next chunk overwrites
    }
}

// ---------------------------------------------------------------------------
// k_scatter: per edge compute w = exp(leaky_relu(s_src[s]+s_dst[d])*0.125),
// claim a slot in src's bucket, store (w, dst) as float2.
// ---------------------------------------------------------------------------
__global__ __launch_bounds__(256) void k_scatter(
    const int* __restrict__ src_arr, const int* __restrict__ dst_arr,
    const float* __restrict__ s_src, const float* __restrict__ s_dst,
    int* __restrict__ cursor, float2* __restrict__ wd, int n_edges)
{
    int e = blockIdx.x * 256 + threadIdx.x;
    if (e >= n_edges) return;
    int s = src_arr[e], d = dst_arr[e];
    float sc = s_src[s] + s_dst[d];
    float lr = sc > 0.f ? sc : ALPHA * sc;
    float w  = expf(lr * INV_SQRT_F);
    int p = atomicAdd(&cursor[s], 1);
    wd[p] = make_float2(w, __int_as_float(d));
}

// ---------------------------------------------------------------------------
// k_gather: wave per node, lane = feature. Loop the node's edge bucket:
// uniform 8B load of (w,dst), coalesced 256B gather of data[dst]. Epilogue
// folds rowsum division + row_zero fallback (rs==0 also covers underflow).
// ---------------------------------------------------------------------------
__global__ __launch_bounds__(256) void k_gather(
    const float2* __restrict__ wd, const int* __restrict__ start,
    const int* __restrict__ deg, const float* __restrict__ data,
    float* __restrict__ out, int n_nodes)
{
    const int wv_ = threadIdx.x >> 6, lane = threadIdx.x & 63;
    const int n = blockIdx.x * 4 + wv_;
    if (n >= n_nodes) return;
    const int s0 = start[n];
    const int cnt = deg[n];
    float acc = 0.f, rs = 0.f;
    for (int j = 0; j < cnt; ++j) {
        float2 e = wd[s0 + j];                 // wave-uniform 8B load
        float w = e.x;
        int d = __float_as_int(e.y);
        acc = fmaf(w, data[(size_t)d * OUT_F + lane], acc);  // coalesced 256B
        rs += w;
    }
    size_t o = (size_t)n * OUT_F + lane;
    out[o] = (rs == 0.f) ? data[o] : acc / rs;
}

extern "C" void kernel_launch(void* const* d_in, const int* in_sizes, int n_in,
                              void* d_out, int out_size, void* d_ws, size_t ws_size,
                              hipStream_t stream)
{
    const float* h   = (const float*)d_in[0];
    const int*   adj = (const int*)  d_in[1];   // (2,E) int32
    const float* W   = (const float*)d_in[2];   // (64,128)
    const float* b   = (const float*)d_in[3];   // (64,)
    const float* a   = (const float*)d_in[4];   // (1,128)
    float* out = (float*)d_out;

    const int n_nodes = in_sizes[0] / IN_F;
    const int n_edges = in_sizes[1] / 2;
    const int* src = adj;
    const int* dst = adj + n_edges;

    // workspace layout (16B-aligned chunks):
    // data[N*64] f32 | wd[E] float2 | s_src[N] | s_dst[N] | deg[N] | start[N] | cursor[N]
    char* p = (char*)d_ws;
    float*  data   = (float*)p;            p += (size_t)n_nodes * OUT_F * 4;
    float2* wd     = (float2*)p;           p += (size_t)n_edges * 8;
    float*  s_src  = (float*)p;            p += (size_t)n_nodes * 4;
    float*  s_dst  = (float*)p;            p += (size_t)n_nodes * 4;
    int*    deg    = (int*)p;              p += (size_t)n_nodes * 4;
    int*    start  = (int*)p;              p += (size_t)n_nodes * 4;
    int*    cursor = (int*)p;              p += (size_t)n_nodes * 4;

    hipMemsetAsync(deg, 0, (size_t)n_nodes * sizeof(int), stream);

    const int g_lin = max((n_nodes + 15) / 16, (n_edges + 255) / 256);
    k_linear<<<g_lin, 256, 0, stream>>>(h, W, b, a, src, data, s_src, s_dst,
                                        deg, n_nodes, n_edges);

    k_scan<<<1, 1024, 0, stream>>>(deg, start, cursor, n_nodes);

    k_scatter<<<(n_edges + 255) / 256, 256, 0, stream>>>(
        src, dst, s_src, s_dst, cursor, wd, n_edges);

    k_gather<<<(n_nodes + 3) / 4, 256, 0, stream>>>(
        wd, start, deg, data, out, n_nodes);
}

// Round 3
// 237.268 us; speedup vs baseline: 1.5152x; 1.3282x over previous
//
#include <hip/hip_runtime.h>
#include <hip/hip_fp16.h>
#include <math.h>

#define IN_F 128
#define OUT_F 64
#define ALPHA 0.2f
#define INV_SQRT_F 0.125f   // 1/sqrt(OUT_F)
#define W_STRIDE 132        // pad: lanes' b128 starts spread over banks within 8-lane groups
#define ROWS_PB 48          // nodes per block (12 per wave)

// ---------------------------------------------------------------------------
// k_linear: data = h@W^T + b ; s_src/s_dst projections; fused deg histogram.
// h tile staged in LDS via coalesced float4; broadcast b128 reads (no pad
// needed — uniform address = broadcast). 12 nodes/wave: 13 LDS reads per
// 48 FMAs -> VALU-bound. Also writes half-precision copy data_h for gather.
// ---------------------------------------------------------------------------
__global__ __launch_bounds__(256) void k_linear(
    const float* __restrict__ h, const float* __restrict__ W,
    const float* __restrict__ b, const float* __restrict__ a,
    const int* __restrict__ src,
    float* __restrict__ data, __half* __restrict__ data_h,
    float* __restrict__ s_src, float* __restrict__ s_dst,
    int* __restrict__ deg, int n_nodes, int n_edges)
{
    __shared__ float Wl[OUT_F * W_STRIDE];   // 33792 B
    __shared__ float hlds[ROWS_PB * IN_F];   // 24576 B, total 58368 B
    const int tid = threadIdx.x;

    // fused histogram (deg pre-zeroed by memset)
    for (int e = blockIdx.x * 256 + tid; e < n_edges; e += gridDim.x * 256)
        atomicAdd(&deg[src[e]], 1);

    // stage W (64x128), coalesced float4
    for (int i = tid * 4; i < OUT_F * IN_F; i += 1024) {
        int f = i >> 7, k = i & 127;
        *(float4*)&Wl[f * W_STRIDE + k] = *(const float4*)&W[i];
    }
    // stage h tile (48 rows), coalesced float4
    const int node0 = blockIdx.x * ROWS_PB;
    for (int i = tid * 4; i < ROWS_PB * IN_F; i += 1024) {
        int r = i >> 7, k = i & 127;
        int n = node0 + r;
        float4 v = make_float4(0.f, 0.f, 0.f, 0.f);
        if (n < n_nodes) v = *(const float4*)&h[(size_t)n * IN_F + k];
        *(float4*)&hlds[r * IN_F + k] = v;
    }
    __syncthreads();

    const int wv = tid >> 6, f = tid & 63;
    const int r0 = wv * 12;
    float acc[12];
    #pragma unroll
    for (int i = 0; i < 12; ++i) acc[i] = 0.f;
    const float4* __restrict__ wp = (const float4*)&Wl[f * W_STRIDE];
    const float4* __restrict__ hp = (const float4*)&hlds[r0 * IN_F];

    #pragma unroll 2
    for (int c = 0; c < 32; ++c) {
        float4 w4 = wp[c];
        #pragma unroll
        for (int i = 0; i < 12; ++i) {
            float4 x = hp[i * 32 + c];   // broadcast (wave-uniform) LDS read
            acc[i] = fmaf(w4.x, x.x, fmaf(w4.y, x.y,
                     fmaf(w4.z, x.z, fmaf(w4.w, x.w, acc[i]))));
        }
    }

    const float bv = b[f], as_ = a[f], ad_ = a[OUT_F + f];
    #pragma unroll
    for (int i = 0; i < 12; ++i) {
        int n = node0 + r0 + i;
        float v = acc[i] + bv;
        float ps = v * as_, pd = v * ad_;
        #pragma unroll
        for (int m = 32; m >= 1; m >>= 1) {
            ps += __shfl_xor(ps, m, 64);
            pd += __shfl_xor(pd, m, 64);
        }
        if (n < n_nodes) {
            size_t o = (size_t)n * OUT_F + f;
            data[o]   = v;
            data_h[o] = __float2half(v);
            if (f == 0) { s_src[n] = ps; s_dst[n] = pd; }
        }
    }
}

// ---------------------------------------------------------------------------
// Multi-block scan, 2048 elements per block.
// ---------------------------------------------------------------------------
__global__ __launch_bounds__(256) void k_scan1(
    const int* __restrict__ deg, int* __restrict__ bsum, int n)
{
    const int tid = threadIdx.x, base = blockIdx.x * 2048;
    int s = 0;
    #pragma unroll
    for (int i = 0; i < 8; ++i) {
        int idx = base + tid + i * 256;
        s += (idx < n) ? deg[idx] : 0;
    }
    #pragma unroll
    for (int m = 32; m >= 1; m >>= 1) s += __shfl_xor(s, m, 64);
    __shared__ int ws[4];
    if ((tid & 63) == 0) ws[tid >> 6] = s;
    __syncthreads();
    if (tid == 0) bsum[blockIdx.x] = ws[0] + ws[1] + ws[2] + ws[3];
}

__global__ void k_scan2(int* bsum, int nb)   // nb <= 64; one wave
{
    const int lane = threadIdx.x;
    int v = (lane < nb) ? bsum[lane] : 0;
    int x = v;
    #pragma unroll
    for (int off = 1; off < 64; off <<= 1) {
        int t = __shfl_up(x, off, 64);
        if (lane >= off) x += t;
    }
    if (lane < nb) bsum[lane] = x - v;   // exclusive, in place
}

__global__ __launch_bounds__(256) void k_scan3(
    const int* __restrict__ deg, const int* __restrict__ bsum,
    int* __restrict__ start, int* __restrict__ cursor, int n)
{
    const int tid = threadIdx.x;
    const int base = blockIdx.x * 2048 + tid * 8;   // deg padded; OOB masked
    int4 a4 = *(const int4*)&deg[base];
    int4 b4 = *(const int4*)&deg[base + 4];
    int v[8] = {a4.x, a4.y, a4.z, a4.w, b4.x, b4.y, b4.z, b4.w};
    int p[8], s = 0;
    #pragma unroll
    for (int i = 0; i < 8; ++i) {
        int val = (base + i < n) ? v[i] : 0;
        p[i] = s; s += val;
    }
    const int lane = tid & 63, wv = tid >> 6;
    int x = s;
    #pragma unroll
    for (int off = 1; off < 64; off <<= 1) {
        int t = __shfl_up(x, off, 64);
        if (lane >= off) x += t;
    }
    __shared__ int wsum[4];
    if (lane == 63) wsum[wv] = x;
    __syncthreads();
    int woff = 0;
    for (int k = 0; k < 4; ++k) woff += (k < wv) ? wsum[k] : 0;
    const int off0 = bsum[blockIdx.x] + woff + (x - s);
    int o[8];
    #pragma unroll
    for (int i = 0; i < 8; ++i) o[i] = off0 + p[i];
    // arrays padded to block multiple: unconditional vector stores are safe
    *(int4*)&start[base]      = make_int4(o[0], o[1], o[2], o[3]);
    *(int4*)&start[base + 4]  = make_int4(o[4], o[5], o[6], o[7]);
    *(int4*)&cursor[base]     = make_int4(o[0], o[1], o[2], o[3]);
    *(int4*)&cursor[base + 4] = make_int4(o[4], o[5], o[6], o[7]);
}

// ---------------------------------------------------------------------------
// k_scatter: bucket edge dst ids by src (4B payload only; w recomputed later)
// ---------------------------------------------------------------------------
__global__ __launch_bounds__(256) void k_scatter(
    const int* __restrict__ src_arr, const int* __restrict__ dst_arr,
    int* __restrict__ cursor, int* __restrict__ dsts, int n_edges)
{
    int e = blockIdx.x * 256 + threadIdx.x;
    if (e >= n_edges) return;
    int p = atomicAdd(&cursor[src_arr[e]], 1);
    dsts[p] = dst_arr[e];
}

// ---------------------------------------------------------------------------
// k_gather: wave per node, lane = feature. Recompute w from s_src/s_dst
// (uniform f32 loads, exact); gather half rows (128B). 4x unrolled.
// ---------------------------------------------------------------------------
__device__ __forceinline__ float edge_w(float sc) {
    float lr = sc > 0.f ? sc : ALPHA * sc;
    return __expf(lr * INV_SQRT_F);
}

__global__ __launch_bounds__(256) void k_gather(
    const int* __restrict__ dsts, const int* __restrict__ start,
    const int* __restrict__ deg, const __half* __restrict__ data_h,
    const float* __restrict__ data, const float* __restrict__ s_dst,
    const float* __restrict__ s_src, float* __restrict__ out, int n_nodes)
{
    const int wv = threadIdx.x >> 6, lane = threadIdx.x & 63;
    const int n = blockIdx.x * 4 + wv;
    if (n >= n_nodes) return;
    const int s0 = start[n], cnt = deg[n];
    const float ssrc = s_src[n];
    float acc = 0.f, rs = 0.f;
    int j = 0;
    for (; j + 4 <= cnt; j += 4) {
        int d0 = dsts[s0 + j],     d1 = dsts[s0 + j + 1];
        int d2 = dsts[s0 + j + 2], d3 = dsts[s0 + j + 3];
        float w0 = edge_w(ssrc + s_dst[d0]);
        float w1 = edge_w(ssrc + s_dst[d1]);
        float w2 = edge_w(ssrc + s_dst[d2]);
        float w3 = edge_w(ssrc + s_dst[d3]);
        float x0 = __half2float(data_h[(size_t)d0 * OUT_F + lane]);
        float x1 = __half2float(data_h[(size_t)d1 * OUT_F + lane]);
        float x2 = __half2float(data_h[(size_t)d2 * OUT_F + lane]);
        float x3 = __half2float(data_h[(size_t)d3 * OUT_F + lane]);
        acc = fmaf(w0, x0, acc); rs += w0;
        acc = fmaf(w1, x1, acc); rs += w1;
        acc = fmaf(w2, x2, acc); rs += w2;
        acc = fmaf(w3, x3, acc); rs += w3;
    }
    for (; j < cnt; ++j) {
        int d = dsts[s0 + j];
        float w = edge_w(ssrc + s_dst[d]);
        acc = fmaf(w, __half2float(data_h[(size_t)d * OUT_F + lane]), acc);
        rs += w;
    }
    size_t o = (size_t)n * OUT_F + lane;
    out[o] = (rs == 0.f) ? data[o] : acc / rs;
}

extern "C" void kernel_launch(void* const* d_in, const int* in_sizes, int n_in,
                              void* d_out, int out_size, void* d_ws, size_t ws_size,
                              hipStream_t stream)
{
    const float* h   = (const float*)d_in[0];
    const int*   adj = (const int*)  d_in[1];   // (2,E) int32
    const float* W   = (const float*)d_in[2];
    const float* b   = (const float*)d_in[3];
    const float* a   = (const float*)d_in[4];
    float* out = (float*)d_out;

    const int n_nodes = in_sizes[0] / IN_F;
    const int n_edges = in_sizes[1] / 2;
    const int* src = adj;
    const int* dst = adj + n_edges;
    const int nb   = (n_nodes + 2047) / 2048;
    const int npad = nb * 2048;

    // ws: data f32 | data_h half | dsts | s_src | s_dst | deg | start | cursor | bsum
    char* p = (char*)d_ws;
    float*  data   = (float*)p;   p += (size_t)n_nodes * OUT_F * 4;
    __half* data_h = (__half*)p;  p += (size_t)n_nodes * OUT_F * 2;
    int*    dsts   = (int*)p;     p += (size_t)n_edges * 4;
    float*  s_src  = (float*)p;   p += (size_t)npad * 4;
    float*  s_dst  = (float*)p;   p += (size_t)npad * 4;
    int*    deg    = (int*)p;     p += (size_t)npad * 4;
    int*    start  = (int*)p;     p += (size_t)npad * 4;
    int*    cursor = (int*)p;     p += (size_t)npad * 4;
    int*    bsum   = (int*)p;     p += 64 * 4;

    hipMemsetAsync(deg, 0, (size_t)n_nodes * sizeof(int), stream);

    const int g_lin = (n_nodes + ROWS_PB - 1) / ROWS_PB;
    k_linear<<<g_lin, 256, 0, stream>>>(h, W, b, a, src, data, data_h,
                                        s_src, s_dst, deg, n_nodes, n_edges);

    k_scan1<<<nb, 256, 0, stream>>>(deg, bsum, n_nodes);
    k_scan2<<<1, 64, 0, stream>>>(bsum, nb);
    k_scan3<<<nb, 256, 0, stream>>>(deg, bsum, start, cursor, n_nodes);

    k_scatter<<<(n_edges + 255) / 256, 256, 0, stream>>>(
        src, dst, cursor, dsts, n_edges);

    k_gather<<<(n_nodes + 3) / 4, 256, 0, stream>>>(
        dsts, start, deg, data_h, data, s_dst, s_src, out, n_nodes);
}

// Round 4
// 215.053 us; speedup vs baseline: 1.6717x; 1.1033x over previous
//
#include <hip/hip_runtime.h>
#include <math.h>

#define IN_F 128
#define OUT_F 64
#define ALPHA 0.2f
#define INV_SQRT_F 0.125f   // 1/sqrt(OUT_F)
#define HS 136              // padded f16 LDS row stride: b128 frag reads = 8 words/bank (optimal)

typedef _Float16 h8  __attribute__((ext_vector_type(8)));
typedef _Float16 h4v __attribute__((ext_vector_type(4)));
typedef _Float16 h2v __attribute__((ext_vector_type(2)));
typedef float    f4  __attribute__((ext_vector_type(4)));

// ---------------------------------------------------------------------------
// k_linear: data_h = f16(h @ W^T + b); s_src/s_dst projections; fused deg
// histogram. MFMA f16 16x16x32: wave = 16 nodes x 64 feats (4 col-tiles x
// 4 K-steps). h/W staged f32->f16 into LDS (stride 136).
// A-frag: A[m=lane&15][k=(lane>>4)*8+j]; B-frag: W[n=lane&15][k=(lane>>4)*8+j]
// (W row-major [out][in] is already B^T-form). C/D: col=lane&15,
// row=(lane>>4)*4+reg  [learn_hip m89].
// ---------------------------------------------------------------------------
__global__ __launch_bounds__(256) void k_linear(
    const float* __restrict__ h, const float* __restrict__ W,
    const float* __restrict__ b, const float* __restrict__ a,
    const int* __restrict__ src, _Float16* __restrict__ data_h,
    float* __restrict__ s_src, float* __restrict__ s_dst,
    int* __restrict__ deg, int n_nodes, int n_edges)
{
    __shared__ _Float16 hsh[64 * HS];   // 17408 B
    __shared__ _Float16 wsh[64 * HS];   // 17408 B  (34816 total -> 4 blocks/CU)
    const int tid = threadIdx.x;
    const int node0 = blockIdx.x * 64;

    // fused histogram (deg pre-zeroed by memset)
    for (int e = blockIdx.x * 256 + tid; e < n_edges; e += gridDim.x * 256)
        atomicAdd(&deg[src[e]], 1);

    // stage W (64x128 f32 -> f16), coalesced float4 reads
    for (int i = tid * 4; i < OUT_F * IN_F; i += 1024) {
        int f = i >> 7, k = i & 127;
        float4 v = *(const float4*)&W[i];
        h4v t; t.x = (_Float16)v.x; t.y = (_Float16)v.y;
               t.z = (_Float16)v.z; t.w = (_Float16)v.w;
        *(h4v*)&wsh[f * HS + k] = t;
    }
    // stage h tile (64 rows), zero-pad past n_nodes
    for (int i = tid * 4; i < 64 * IN_F; i += 1024) {
        int r = i >> 7, k = i & 127;
        int n = node0 + r;
        float4 v = make_float4(0.f, 0.f, 0.f, 0.f);
        if (n < n_nodes) v = *(const float4*)&h[(size_t)n * IN_F + k];
        h4v t; t.x = (_Float16)v.x; t.y = (_Float16)v.y;
               t.z = (_Float16)v.z; t.w = (_Float16)v.w;
        *(h4v*)&hsh[r * HS + k] = t;
    }
    __syncthreads();

    const int wv  = tid >> 6;      // wave -> 16-node row tile
    const int lane = tid & 63;
    const int q   = lane >> 4;     // quad
    const int col = lane & 15;     // m for A / n for B / col for C
    const int r0  = wv * 16;

    f4 acc[4] = {{0.f,0.f,0.f,0.f},{0.f,0.f,0.f,0.f},
                 {0.f,0.f,0.f,0.f},{0.f,0.f,0.f,0.f}};
    #pragma unroll
    for (int kk = 0; kk < 4; ++kk) {
        h8 av = *(const h8*)&hsh[(r0 + col) * HS + kk * 32 + q * 8];
        #pragma unroll
        for (int ct = 0; ct < 4; ++ct) {
            h8 bv = *(const h8*)&wsh[(ct * 16 + col) * HS + kk * 32 + q * 8];
            acc[ct] = __builtin_amdgcn_mfma_f32_16x16x32_f16(av, bv, acc[ct], 0, 0, 0);
        }
    }

    float bb[4], as_[4], ad_[4];
    #pragma unroll
    for (int ct = 0; ct < 4; ++ct) {
        bb[ct]  = b[ct * 16 + col];
        as_[ct] = a[ct * 16 + col];
        ad_[ct] = a[OUT_F + ct * 16 + col];
    }
    #pragma unroll
    for (int reg = 0; reg < 4; ++reg) {
        int n = node0 + r0 + q * 4 + reg;
        float vv[4], ps = 0.f, pd = 0.f;
        #pragma unroll
        for (int ct = 0; ct < 4; ++ct) {
            float v = acc[ct][reg] + bb[ct];
            vv[ct] = v;
            ps = fmaf(v, as_[ct], ps);
            pd = fmaf(v, ad_[ct], pd);
        }
        // reduce over the 16 lanes sharing q (feature dimension)
        #pragma unroll
        for (int m = 1; m <= 8; m <<= 1) {
            ps += __shfl_xor(ps, m, 64);
            pd += __shfl_xor(pd, m, 64);
        }
        if (n < n_nodes) {
            size_t base = (size_t)n * OUT_F + col;
            #pragma unroll
            for (int ct = 0; ct < 4; ++ct)
                data_h[base + ct * 16] = (_Float16)vv[ct];
            if (col == 0) { s_src[n] = ps; s_dst[n] = pd; }
        }
    }
}

// ---------------------------------------------------------------------------
// Multi-block scan of deg -> start/cursor (2048 elems per block).
// ---------------------------------------------------------------------------
__global__ __launch_bounds__(256) void k_scan1(
    const int* __restrict__ deg, int* __restrict__ bsum, int n)
{
    const int tid = threadIdx.x, base = blockIdx.x * 2048;
    int s = 0;
    #pragma unroll
    for (int i = 0; i < 8; ++i) {
        int idx = base + tid + i * 256;
        s += (idx < n) ? deg[idx] : 0;
    }
    #pragma unroll
    for (int m = 32; m >= 1; m >>= 1) s += __shfl_xor(s, m, 64);
    __shared__ int ws[4];
    if ((tid & 63) == 0) ws[tid >> 6] = s;
    __syncthreads();
    if (tid == 0) bsum[blockIdx.x] = ws[0] + ws[1] + ws[2] + ws[3];
}

__global__ void k_scan2(int* bsum, int nb)   // nb <= 64; one wave
{
    const int lane = threadIdx.x;
    int v = (lane < nb) ? bsum[lane] : 0;
    int x = v;
    #pragma unroll
    for (int off = 1; off < 64; off <<= 1) {
        int t = __shfl_up(x, off, 64);
        if (lane >= off) x += t;
    }
    if (lane < nb) bsum[lane] = x - v;
}

__global__ __launch_bounds__(256) void k_scan3(
    const int* __restrict__ deg, const int* __restrict__ bsum,
    int* __restrict__ start, int* __restrict__ cursor, int n)
{
    const int tid = threadIdx.x;
    const int base = blockIdx.x * 2048 + tid * 8;   // arrays padded to npad
    int4 a4 = *(const int4*)&deg[base];
    int4 b4 = *(const int4*)&deg[base + 4];
    int v[8] = {a4.x, a4.y, a4.z, a4.w, b4.x, b4.y, b4.z, b4.w};
    int p[8], s = 0;
    #pragma unroll
    for (int i = 0; i < 8; ++i) {
        int val = (base + i < n) ? v[i] : 0;
        p[i] = s; s += val;
    }
    const int lane = tid & 63, wv = tid >> 6;
    int x = s;
    #pragma unroll
    for (int off = 1; off < 64; off <<= 1) {
        int t = __shfl_up(x, off, 64);
        if (lane >= off) x += t;
    }
    __shared__ int wsum[4];
    if (lane == 63) wsum[wv] = x;
    __syncthreads();
    int woff = 0;
    for (int k = 0; k < 4; ++k) woff += (k < wv) ? wsum[k] : 0;
    const int off0 = bsum[blockIdx.x] + woff + (x - s);
    int o[8];
    #pragma unroll
    for (int i = 0; i < 8; ++i) o[i] = off0 + p[i];
    *(int4*)&start[base]      = make_int4(o[0], o[1], o[2], o[3]);
    *(int4*)&start[base + 4]  = make_int4(o[4], o[5], o[6], o[7]);
    *(int4*)&cursor[base]     = make_int4(o[0], o[1], o[2], o[3]);
    *(int4*)&cursor[base + 4] = make_int4(o[4], o[5], o[6], o[7]);
}

// ---------------------------------------------------------------------------
// k_scatter: bucket dst ids by src (4B payload; w recomputed in gather)
// ---------------------------------------------------------------------------
__global__ __launch_bounds__(256) void k_scatter(
    const int* __restrict__ src_arr, const int* __restrict__ dst_arr,
    int* __restrict__ cursor, int* __restrict__ dsts, int n_edges)
{
    int e = blockIdx.x * 256 + threadIdx.x;
    if (e >= n_edges) return;
    int p = atomicAdd(&cursor[src_arr[e]], 1);
    dsts[p] = dst_arr[e];
}

// ---------------------------------------------------------------------------
// k_gather: wave per node; 2 edges per iteration (lane parity = edge parity,
// each lane covers 2 features via __half2 load -> 256B/instr). Halves merged
// with one shfl_xor(32) at the end.
// ---------------------------------------------------------------------------
__device__ __forceinline__ float edge_w(float sc) {
    float lr = sc > 0.f ? sc : ALPHA * sc;
    return __expf(lr * INV_SQRT_F);
}

__global__ __launch_bounds__(256) void k_gather(
    const int* __restrict__ dsts, const int* __restrict__ start,
    const int* __restrict__ deg, const _Float16* __restrict__ data_h,
    const float* __restrict__ s_dst, const float* __restrict__ s_src,
    float* __restrict__ out, int n_nodes)
{
    const int wv = threadIdx.x >> 6, lane = threadIdx.x & 63;
    const int n = blockIdx.x * 4 + wv;
    if (n >= n_nodes) return;
    const int s0 = start[n], cnt = deg[n];
    const float ssrc = s_src[n];
    const int par = lane >> 5;       // edge parity
    const int fh  = lane & 31;       // features 2fh, 2fh+1
    float ax = 0.f, ay = 0.f, rs = 0.f;
    const int npair = cnt >> 1;
    int t = 0;
    for (; t + 2 <= npair; t += 2) {
        int d0 = dsts[s0 + 2 * t + par];
        int d1 = dsts[s0 + 2 * t + 2 + par];
        float w0 = edge_w(ssrc + s_dst[d0]);
        float w1 = edge_w(ssrc + s_dst[d1]);
        h2v x0 = *(const h2v*)&data_h[(size_t)d0 * OUT_F + 2 * fh];
        h2v x1 = *(const h2v*)&data_h[(size_t)d1 * OUT_F + 2 * fh];
        ax = fmaf(w0, (float)x0.x, ax); ay = fmaf(w0, (float)x0.y, ay); rs += w0;
        ax = fmaf(w1, (float)x1.x, ax); ay = fmaf(w1, (float)x1.y, ay); rs += w1;
    }
    for (; t < npair; ++t) {
        int d0 = dsts[s0 + 2 * t + par];
        float w0 = edge_w(ssrc + s_dst[d0]);
        h2v x0 = *(const h2v*)&data_h[(size_t)d0 * OUT_F + 2 * fh];
        ax = fmaf(w0, (float)x0.x, ax); ay = fmaf(w0, (float)x0.y, ay); rs += w0;
    }
    if ((cnt & 1) && par == 0) {
        int d0 = dsts[s0 + cnt - 1];
        float w0 = edge_w(ssrc + s_dst[d0]);
        h2v x0 = *(const h2v*)&data_h[(size_t)d0 * OUT_F + 2 * fh];
        ax = fmaf(w0, (float)x0.x, ax); ay = fmaf(w0, (float)x0.y, ay); rs += w0;
    }
    ax += __shfl_xor(ax, 32, 64);
    ay += __shfl_xor(ay, 32, 64);
    rs += __shfl_xor(rs, 32, 64);
    if (par == 0) {
        size_t o = (size_t)n * OUT_F + 2 * fh;
        float2 r;
        if (rs == 0.f) { r.x = (float)data_h[o]; r.y = (float)data_h[o + 1]; }
        else           { r.x = ax / rs;          r.y = ay / rs; }
        *(float2*)&out[o] = r;
    }
}

extern "C" void kernel_launch(void* const* d_in, const int* in_sizes, int n_in,
                              void* d_out, int out_size, void* d_ws, size_t ws_size,
                              hipStream_t stream)
{
    const float* h   = (const float*)d_in[0];
    const int*   adj = (const int*)  d_in[1];   // (2,E) int32
    const float* W   = (const float*)d_in[2];
    const float* b   = (const float*)d_in[3];
    const float* a   = (const float*)d_in[4];
    float* out = (float*)d_out;

    const int n_nodes = in_sizes[0] / IN_F;
    const int n_edges = in_sizes[1] / 2;
    const int* src = adj;
    const int* dst = adj + n_edges;
    const int nb   = (n_nodes + 2047) / 2048;
    const int npad = nb * 2048;

    // ws: data_h f16 | dsts | s_src | s_dst | deg | start | cursor | bsum
    char* p = (char*)d_ws;
    _Float16* data_h = (_Float16*)p; p += (size_t)n_nodes * OUT_F * 2;
    int*    dsts   = (int*)p;        p += (size_t)n_edges * 4;
    float*  s_src  = (float*)p;      p += (size_t)npad * 4;
    float*  s_dst  = (float*)p;      p += (size_t)npad * 4;
    int*    deg    = (int*)p;        p += (size_t)npad * 4;
    int*    start  = (int*)p;        p += (size_t)npad * 4;
    int*    cursor = (int*)p;        p += (size_t)npad * 4;
    int*    bsum   = (int*)p;        p += 64 * 4;

    hipMemsetAsync(deg, 0, (size_t)n_nodes * sizeof(int), stream);

    const int g_lin = (n_nodes + 63) / 64;
    k_linear<<<g_lin, 256, 0, stream>>>(h, W, b, a, src, data_h,
                                        s_src, s_dst, deg, n_nodes, n_edges);

    k_scan1<<<nb, 256, 0, stream>>>(deg, bsum, n_nodes);
    k_scan2<<<1, 64, 0, stream>>>(bsum, nb);
    k_scan3<<<nb, 256, 0, stream>>>(deg, bsum, start, cursor, n_nodes);

    k_scatter<<<(n_edges + 255) / 256, 256, 0, stream>>>(
        src, dst, cursor, dsts, n_edges);

    k_gather<<<(n_nodes + 3) / 4, 256, 0, stream>>>(
        dsts, start, deg, data_h, s_dst, s_src, out, n_nodes);
}

// Round 5
// 180.039 us; speedup vs baseline: 1.9968x; 1.1945x over previous
//
#include <hip/hip_runtime.h>
#include <math.h>

#define IN_F 128
#define OUT_F 64
#define ALPHA 0.2f
#define INV_SQRT_F 0.125f   // 1/sqrt(OUT_F)
#define HS 136              // padded f16 LDS row stride

typedef _Float16 h8  __attribute__((ext_vector_type(8)));
typedef _Float16 h4v __attribute__((ext_vector_type(4)));
typedef float    f2v __attribute__((ext_vector_type(2)));
typedef float    f4  __attribute__((ext_vector_type(4)));

// ---------------------------------------------------------------------------
// k_linear: data_h = f16(h @ W^T + b); s_src/s_dst projections; fused deg
// histogram whose atomic RETURN VALUE is the edge's rank within its src
// bucket (saves the scatter-side atomic). MFMA f16 16x16x32.
// ---------------------------------------------------------------------------
__global__ __launch_bounds__(256) void k_linear(
    const float* __restrict__ h, const float* __restrict__ W,
    const float* __restrict__ b, const float* __restrict__ a,
    const int* __restrict__ src, _Float16* __restrict__ data_h,
    float* __restrict__ s_src, float* __restrict__ s_dst,
    int* __restrict__ deg, int* __restrict__ rank,
    int n_nodes, int n_edges)
{
    __shared__ _Float16 hsh[64 * HS];   // 17408 B
    __shared__ _Float16 wsh[64 * HS];   // 17408 B
    const int tid = threadIdx.x;
    const int node0 = blockIdx.x * 64;

    // fused histogram + rank assignment (deg pre-zeroed by memset)
    for (int e = blockIdx.x * 256 + tid; e < n_edges; e += gridDim.x * 256) {
        int r = atomicAdd(&deg[src[e]], 1);
        rank[e] = r;                      // coalesced
    }

    // stage W (64x128 f32 -> f16)
    for (int i = tid * 4; i < OUT_F * IN_F; i += 1024) {
        int f = i >> 7, k = i & 127;
        float4 v = *(const float4*)&W[i];
        h4v t; t.x = (_Float16)v.x; t.y = (_Float16)v.y;
               t.z = (_Float16)v.z; t.w = (_Float16)v.w;
        *(h4v*)&wsh[f * HS + k] = t;
    }
    // stage h tile (64 rows)
    for (int i = tid * 4; i < 64 * IN_F; i += 1024) {
        int r = i >> 7, k = i & 127;
        int n = node0 + r;
        float4 v = make_float4(0.f, 0.f, 0.f, 0.f);
        if (n < n_nodes) v = *(const float4*)&h[(size_t)n * IN_F + k];
        h4v t; t.x = (_Float16)v.x; t.y = (_Float16)v.y;
               t.z = (_Float16)v.z; t.w = (_Float16)v.w;
        *(h4v*)&hsh[r * HS + k] = t;
    }
    __syncthreads();

    const int wv  = tid >> 6;
    const int lane = tid & 63;
    const int q   = lane >> 4;
    const int col = lane & 15;
    const int r0  = wv * 16;

    f4 acc[4] = {{0.f,0.f,0.f,0.f},{0.f,0.f,0.f,0.f},
                 {0.f,0.f,0.f,0.f},{0.f,0.f,0.f,0.f}};
    #pragma unroll
    for (int kk = 0; kk < 4; ++kk) {
        h8 av = *(const h8*)&hsh[(r0 + col) * HS + kk * 32 + q * 8];
        #pragma unroll
        for (int ct = 0; ct < 4; ++ct) {
            h8 bv = *(const h8*)&wsh[(ct * 16 + col) * HS + kk * 32 + q * 8];
            acc[ct] = __builtin_amdgcn_mfma_f32_16x16x32_f16(av, bv, acc[ct], 0, 0, 0);
        }
    }

    float bb[4], as_[4], ad_[4];
    #pragma unroll
    for (int ct = 0; ct < 4; ++ct) {
        bb[ct]  = b[ct * 16 + col];
        as_[ct] = a[ct * 16 + col];
        ad_[ct] = a[OUT_F + ct * 16 + col];
    }
    #pragma unroll
    for (int reg = 0; reg < 4; ++reg) {
        int n = node0 + r0 + q * 4 + reg;
        float vv[4], ps = 0.f, pd = 0.f;
        #pragma unroll
        for (int ct = 0; ct < 4; ++ct) {
            float v = acc[ct][reg] + bb[ct];
            vv[ct] = v;
            ps = fmaf(v, as_[ct], ps);
            pd = fmaf(v, ad_[ct], pd);
        }
        #pragma unroll
        for (int m = 1; m <= 8; m <<= 1) {
            ps += __shfl_xor(ps, m, 64);
            pd += __shfl_xor(pd, m, 64);
        }
        if (n < n_nodes) {
            size_t base = (size_t)n * OUT_F + col;
            #pragma unroll
            for (int ct = 0; ct < 4; ++ct)
                data_h[base + ct * 16] = (_Float16)vv[ct];
            if (col == 0) { s_src[n] = ps; s_dst[n] = pd; }
        }
    }
}

// ---------------------------------------------------------------------------
// Multi-block scan of deg -> start (2048 elems per block).
// ---------------------------------------------------------------------------
__global__ __launch_bounds__(256) void k_scan1(
    const int* __restrict__ deg, int* __restrict__ bsum, int n)
{
    const int tid = threadIdx.x, base = blockIdx.x * 2048;
    int s = 0;
    #pragma unroll
    for (int i = 0; i < 8; ++i) {
        int idx = base + tid + i * 256;
        s += (idx < n) ? deg[idx] : 0;
    }
    #pragma unroll
    for (int m = 32; m >= 1; m >>= 1) s += __shfl_xor(s, m, 64);
    __shared__ int ws[4];
    if ((tid & 63) == 0) ws[tid >> 6] = s;
    __syncthreads();
    if (tid == 0) bsum[blockIdx.x] = ws[0] + ws[1] + ws[2] + ws[3];
}

__global__ void k_scan2(int* bsum, int nb)   // nb <= 64; one wave
{
    const int lane = threadIdx.x;
    int v = (lane < nb) ? bsum[lane] : 0;
    int x = v;
    #pragma unroll
    for (int off = 1; off < 64; off <<= 1) {
        int t = __shfl_up(x, off, 64);
        if (lane >= off) x += t;
    }
    if (lane < nb) bsum[lane] = x - v;
}

__global__ __launch_bounds__(256) void k_scan3(
    const int* __restrict__ deg, const int* __restrict__ bsum,
    int* __restrict__ start, int n)
{
    const int tid = threadIdx.x;
    const int base = blockIdx.x * 2048 + tid * 8;   // arrays padded to npad
    int4 a4 = *(const int4*)&deg[base];
    int4 b4 = *(const int4*)&deg[base + 4];
    int v[8] = {a4.x, a4.y, a4.z, a4.w, b4.x, b4.y, b4.z, b4.w};
    int p[8], s = 0;
    #pragma unroll
    for (int i = 0; i < 8; ++i) {
        int val = (base + i < n) ? v[i] : 0;
        p[i] = s; s += val;
    }
    const int lane = tid & 63, wv = tid >> 6;
    int x = s;
    #pragma unroll
    for (int off = 1; off < 64; off <<= 1) {
        int t = __shfl_up(x, off, 64);
        if (lane >= off) x += t;
    }
    __shared__ int wsum[4];
    if (lane == 63) wsum[wv] = x;
    __syncthreads();
    int woff = 0;
    for (int k = 0; k < 4; ++k) woff += (k < wv) ? wsum[k] : 0;
    const int off0 = bsum[blockIdx.x] + woff + (x - s);
    int o[8];
    #pragma unroll
    for (int i = 0; i < 8; ++i) o[i] = off0 + p[i];
    *(int4*)&start[base]     = make_int4(o[0], o[1], o[2], o[3]);
    *(int4*)&start[base + 4] = make_int4(o[4], o[5], o[6], o[7]);
}

// ---------------------------------------------------------------------------
// k_scatter: p = start[src] + rank (NO atomic); w = exp(leaky_relu(score));
// nontemporal 8B store of (w, dst) -> streams past per-XCD L2s so partial
// lines merge at the memory-side cache (kills the 64B-per-store writeback).
// 2 edges per thread for MLP.
// ---------------------------------------------------------------------------
__device__ __forceinline__ float edge_w(float sc) {
    float lr = sc > 0.f ? sc : ALPHA * sc;
    return __expf(lr * INV_SQRT_F);
}

__global__ __launch_bounds__(256) void k_scatter(
    const int* __restrict__ src_arr, const int* __restrict__ dst_arr,
    const int* __restrict__ rank, const int* __restrict__ start,
    const float* __restrict__ s_src, const float* __restrict__ s_dst,
    f2v* __restrict__ wd, int n_edges)
{
    const int e = (blockIdx.x * 256 + threadIdx.x) * 2;
    if (e + 2 <= n_edges) {
        int2 s2 = *(const int2*)&src_arr[e];
        int2 d2 = *(const int2*)&dst_arr[e];
        int2 r2 = *(const int2*)&rank[e];
        int p0 = start[s2.x] + r2.x;
        int p1 = start[s2.y] + r2.y;
        float w0 = edge_w(s_src[s2.x] + s_dst[d2.x]);
        float w1 = edge_w(s_src[s2.y] + s_dst[d2.y]);
        f2v v0; v0.x = w0; v0.y = __int_as_float(d2.x);
        f2v v1; v1.x = w1; v1.y = __int_as_float(d2.y);
        __builtin_nontemporal_store(v0, &wd[p0]);
        __builtin_nontemporal_store(v1, &wd[p1]);
    } else if (e < n_edges) {
        int s = src_arr[e], d = dst_arr[e];
        int p = start[s] + rank[e];
        float w = edge_w(s_src[s] + s_dst[d]);
        f2v v; v.x = w; v.y = __int_as_float(d);
        __builtin_nontemporal_store(v, &wd[p]);
    }
}

// ---------------------------------------------------------------------------
// k_gather: wave per node; lane -> (quarter q, 4 features). 4 edges in
// flight per iteration (x2 unroll = 8); merge quarters with 2 shfl_xors.
// ---------------------------------------------------------------------------
__global__ __launch_bounds__(256) void k_gather(
    const f2v* __restrict__ wd, const int* __restrict__ start,
    const int* __restrict__ deg, const _Float16* __restrict__ data_h,
    float* __restrict__ out, int n_nodes)
{
    const int wv = threadIdx.x >> 6, lane = threadIdx.x & 63;
    const int n = blockIdx.x * 4 + wv;
    if (n >= n_nodes) return;
    const int s0 = start[n], cnt = deg[n];
    const int q = lane >> 4, fq = lane & 15;

    float a0 = 0.f, a1 = 0.f, a2 = 0.f, a3 = 0.f, rs = 0.f;
    int t = 0;
    for (; t + 8 <= cnt; t += 8) {
        f2v e0 = wd[s0 + t + q];
        f2v e1 = wd[s0 + t + 4 + q];
        float w0 = e0.x; int d0 = __float_as_int(e0.y);
        float w1 = e1.x; int d1 = __float_as_int(e1.y);
        h4v x0 = *(const h4v*)&data_h[(size_t)d0 * OUT_F + 4 * fq];
        h4v x1 = *(const h4v*)&data_h[(size_t)d1 * OUT_F + 4 * fq];
        a0 = fmaf(w0, (float)x0.x, a0); a1 = fmaf(w0, (float)x0.y, a1);
        a2 = fmaf(w0, (float)x0.z, a2); a3 = fmaf(w0, (float)x0.w, a3);
        a0 = fmaf(w1, (float)x1.x, a0); a1 = fmaf(w1, (float)x1.y, a1);
        a2 = fmaf(w1, (float)x1.z, a2); a3 = fmaf(w1, (float)x1.w, a3);
        rs += w0 + w1;
    }
    for (; t + 4 <= cnt; t += 4) {
        f2v e0 = wd[s0 + t + q];
        float w0 = e0.x; int d0 = __float_as_int(e0.y);
        h4v x0 = *(const h4v*)&data_h[(size_t)d0 * OUT_F + 4 * fq];
        a0 = fmaf(w0, (float)x0.x, a0); a1 = fmaf(w0, (float)x0.y, a1);
        a2 = fmaf(w0, (float)x0.z, a2); a3 = fmaf(w0, (float)x0.w, a3);
        rs += w0;
    }
    const int rem = cnt - t;        // 0..3
    if (q < rem) {
        f2v e0 = wd[s0 + t + q];
        float w0 = e0.x; int d0 = __float_as_int(e0.y);
        h4v x0 = *(const h4v*)&data_h[(size_t)d0 * OUT_F + 4 * fq];
        a0 = fmaf(w0, (float)x0.x, a0); a1 = fmaf(w0, (float)x0.y, a1);
        a2 = fmaf(w0, (float)x0.z, a2); a3 = fmaf(w0, (float)x0.w, a3);
        rs += w0;
    }
    // merge the 4 quarters
    a0 += __shfl_xor(a0, 16, 64); a0 += __shfl_xor(a0, 32, 64);
    a1 += __shfl_xor(a1, 16, 64); a1 += __shfl_xor(a1, 32, 64);
    a2 += __shfl_xor(a2, 16, 64); a2 += __shfl_xor(a2, 32, 64);
    a3 += __shfl_xor(a3, 16, 64); a3 += __shfl_xor(a3, 32, 64);
    rs += __shfl_xor(rs, 16, 64); rs += __shfl_xor(rs, 32, 64);

    if (q == 0) {
        size_t o = (size_t)n * OUT_F + 4 * fq;
        float4 r;
        if (rs == 0.f) {
            h4v xv = *(const h4v*)&data_h[o];
            r = make_float4((float)xv.x, (float)xv.y, (float)xv.z, (float)xv.w);
        } else {
            float inv = 1.f / rs;
            r = make_float4(a0 * inv, a1 * inv, a2 * inv, a3 * inv);
        }
        *(float4*)&out[o] = r;
    }
}

extern "C" void kernel_launch(void* const* d_in, const int* in_sizes, int n_in,
                              void* d_out, int out_size, void* d_ws, size_t ws_size,
                              hipStream_t stream)
{
    const float* h   = (const float*)d_in[0];
    const int*   adj = (const int*)  d_in[1];   // (2,E) int32
    const float* W   = (const float*)d_in[2];
    const float* b   = (const float*)d_in[3];
    const float* a   = (const float*)d_in[4];
    float* out = (float*)d_out;

    const int n_nodes = in_sizes[0] / IN_F;
    const int n_edges = in_sizes[1] / 2;
    const int* src = adj;
    const int* dst = adj + n_edges;
    const int nb   = (n_nodes + 2047) / 2048;
    const int npad = nb * 2048;

    // ws: data_h f16 | wd f2v[E] | rank[E] | s_src | s_dst | deg | start | bsum
    char* p = (char*)d_ws;
    _Float16* data_h = (_Float16*)p; p += (size_t)n_nodes * OUT_F * 2;
    f2v*    wd     = (f2v*)p;        p += (size_t)n_edges * 8;
    int*    rank   = (int*)p;        p += (size_t)n_edges * 4;
    float*  s_src  = (float*)p;      p += (size_t)npad * 4;
    float*  s_dst  = (float*)p;      p += (size_t)npad * 4;
    int*    deg    = (int*)p;        p += (size_t)npad * 4;
    int*    start  = (int*)p;        p += (size_t)npad * 4;
    int*    bsum   = (int*)p;        p += 64 * 4;

    hipMemsetAsync(deg, 0, (size_t)n_nodes * sizeof(int), stream);

    const int g_lin = (n_nodes + 63) / 64;
    k_linear<<<g_lin, 256, 0, stream>>>(h, W, b, a, src, data_h,
                                        s_src, s_dst, deg, rank,
                                        n_nodes, n_edges);

    k_scan1<<<nb, 256, 0, stream>>>(deg, bsum, n_nodes);
    k_scan2<<<1, 64, 0, stream>>>(bsum, nb);
    k_scan3<<<nb, 256, 0, stream>>>(deg, bsum, start, n_nodes);

    k_scatter<<<(n_edges + 511) / 512, 256, 0, stream>>>(
        src, dst, rank, start, s_src, s_dst, wd, n_edges);

    k_gather<<<(n_nodes + 3) / 4, 256, 0, stream>>>(
        wd, start, deg, data_h, out, n_nodes);
}